// Round 1
// baseline (689.727 us; speedup 1.0000x reference)
//
#include <hip/hip_runtime.h>
#include <hip/hip_bf16.h>

#define E_NUM 8
#define I_DIM 2816
#define D_DIM 1024
#define T_NUM 1024
#define A_TOP 2
#define NPAIR (T_NUM * A_TOP)   // 2048
#define LDSP 72                 // 64 + 8 pad (bf16 elems), row = 144 B

typedef __bf16 bf16x8 __attribute__((ext_vector_type(8)));
typedef float  f32x4  __attribute__((ext_vector_type(4)));

__device__ inline unsigned short f2bf(float f) {
  union { float f; unsigned u; } v; v.f = f;
  unsigned r = v.u + 0x7fffu + ((v.u >> 16) & 1u);   // RNE
  return (unsigned short)(r >> 16);
}
__device__ inline ushort4 f2bf4(float4 v) {
  ushort4 u;
  u.x = f2bf(v.x); u.y = f2bf(v.y); u.z = f2bf(v.z); u.w = f2bf(v.w);
  return u;
}

// ---------------- kernel 1: bucket pairs by expert ----------------
__global__ __launch_bounds__(256) void sort_pairs_kernel(
    const int* __restrict__ eidx, int* __restrict__ meta, int* __restrict__ pairs)
{
  __shared__ int cnt[E_NUM];
  __shared__ int off[E_NUM + 1];
  __shared__ int cur[E_NUM];
  int tid = threadIdx.x;
  if (tid < E_NUM) cnt[tid] = 0;
  __syncthreads();
  for (int p = tid; p < NPAIR; p += 256) atomicAdd(&cnt[eidx[p] & 7], 1);
  __syncthreads();
  if (tid == 0) {
    int s = 0;
    for (int e = 0; e < E_NUM; ++e) { off[e] = s; cur[e] = s; s += cnt[e]; }
    off[E_NUM] = s;
  }
  __syncthreads();
  for (int p = tid; p < NPAIR; p += 256) {
    int e = eidx[p] & 7;
    int pos = atomicAdd(&cur[e], 1);
    pairs[pos] = p;
  }
  __syncthreads();
  if (tid <= E_NUM) meta[tid] = off[tid];
}

// ---------------- kernel 2: h = silu(X w1^T) * (X w3^T), grouped by expert ----
// grid: (22 ntiles, 16 mtiles, 8 experts), block 256 (4 waves, 2x2 of 64x64)
__global__ __launch_bounds__(256) void stage1_kernel(
    const float* __restrict__ x, const float* __restrict__ w1,
    const float* __restrict__ w3, const int* __restrict__ meta,
    const int* __restrict__ pairs, unsigned short* __restrict__ hbuf)
{
  int e = blockIdx.z;
  int off = meta[e];
  int cnt = meta[e + 1] - off;
  int mtile = blockIdx.y;
  if (mtile * 128 >= cnt) return;
  int ntile = blockIdx.x;

  __shared__ alignas(16) unsigned short As[128 * LDSP];
  __shared__ alignas(16) unsigned short B1s[128 * LDSP];
  __shared__ alignas(16) unsigned short B3s[128 * LDSP];
  __shared__ int rowtok[128];

  int tid = threadIdx.x;
  for (int i = tid; i < 128; i += 256) {
    int grow = mtile * 128 + i;
    rowtok[i] = (grow < cnt) ? (pairs[off + grow] >> 1) : -1;  // token = pair/A
  }

  int lane = tid & 63;
  int w = tid >> 6;
  int wm = w >> 1, wn = w & 1;
  int lrow = lane & 15;
  int quad = lane >> 4;

  f32x4 acc1[4][4], acc3[4][4];
#pragma unroll
  for (int i = 0; i < 4; ++i)
#pragma unroll
    for (int j = 0; j < 4; ++j) {
      acc1[i][j] = (f32x4){0.f, 0.f, 0.f, 0.f};
      acc3[i][j] = (f32x4){0.f, 0.f, 0.f, 0.f};
    }

  const float* w1base = w1 + ((size_t)e * I_DIM + (size_t)ntile * 128) * D_DIM;
  const float* w3base = w3 + ((size_t)e * I_DIM + (size_t)ntile * 128) * D_DIM;

  for (int k0 = 0; k0 < D_DIM; k0 += 64) {
    __syncthreads();
#pragma unroll
    for (int c = 0; c < 8; ++c) {
      int id = c * 256 + tid;          // 0..2047
      int row = id >> 4;               // 16 float4-chunks per 64-col row
      int col = (id & 15) * 4;
      int tok = rowtok[row];
      float4 va = make_float4(0.f, 0.f, 0.f, 0.f);
      if (tok >= 0) va = *(const float4*)(x + (size_t)tok * D_DIM + k0 + col);
      *(ushort4*)&As[row * LDSP + col] = f2bf4(va);
      float4 v1 = *(const float4*)(w1base + (size_t)row * D_DIM + k0 + col);
      *(ushort4*)&B1s[row * LDSP + col] = f2bf4(v1);
      float4 v3 = *(const float4*)(w3base + (size_t)row * D_DIM + k0 + col);
      *(ushort4*)&B3s[row * LDSP + col] = f2bf4(v3);
    }
    __syncthreads();
#pragma unroll
    for (int ks = 0; ks < 2; ++ks) {
      int kb = ks * 32 + quad * 8;
      bf16x8 af[4];
#pragma unroll
      for (int mi = 0; mi < 4; ++mi)
        af[mi] = *(const bf16x8*)&As[(wm * 64 + mi * 16 + lrow) * LDSP + kb];
#pragma unroll
      for (int ni = 0; ni < 4; ++ni) {
        bf16x8 b1 = *(const bf16x8*)&B1s[(wn * 64 + ni * 16 + lrow) * LDSP + kb];
#pragma unroll
        for (int mi = 0; mi < 4; ++mi)
          acc1[mi][ni] = __builtin_amdgcn_mfma_f32_16x16x32_bf16(af[mi], b1, acc1[mi][ni], 0, 0, 0);
        bf16x8 b3 = *(const bf16x8*)&B3s[(wn * 64 + ni * 16 + lrow) * LDSP + kb];
#pragma unroll
        for (int mi = 0; mi < 4; ++mi)
          acc3[mi][ni] = __builtin_amdgcn_mfma_f32_16x16x32_bf16(af[mi], b3, acc3[mi][ni], 0, 0, 0);
      }
    }
  }

  // epilogue: h = silu(a1) * a3 -> bf16, rows in sorted order
#pragma unroll
  for (int mi = 0; mi < 4; ++mi) {
#pragma unroll
    for (int r = 0; r < 4; ++r) {
      int lr = wm * 64 + mi * 16 + quad * 4 + r;
      int grow = mtile * 128 + lr;
      if (grow < cnt) {
        size_t base = (size_t)(off + grow) * I_DIM + (size_t)ntile * 128 + wn * 64;
#pragma unroll
        for (int ni = 0; ni < 4; ++ni) {
          float v1 = acc1[mi][ni][r];
          float v3 = acc3[mi][ni][r];
          float hv = (v1 / (1.f + __expf(-v1))) * v3;
          hbuf[base + ni * 16 + lrow] = f2bf(hv);
        }
      }
    }
  }
}

// ---------------- kernel 3: out = h w2^T, scatter rows to out[pair] ---------
// grid: (16 ntiles of 64, 16 mtiles, 8 experts), block 256 (4 waves of 32x64)
__global__ __launch_bounds__(256) void stage2_kernel(
    const unsigned short* __restrict__ hbuf, const float* __restrict__ w2,
    const int* __restrict__ meta, const int* __restrict__ pairs,
    float* __restrict__ out)
{
  int e = blockIdx.z;
  int off = meta[e];
  int cnt = meta[e + 1] - off;
  int mtile = blockIdx.y;
  if (mtile * 128 >= cnt) return;
  int ntile = blockIdx.x;

  __shared__ alignas(16) unsigned short As[128 * LDSP];
  __shared__ alignas(16) unsigned short Bs[64 * LDSP];
  __shared__ int prow[128];

  int tid = threadIdx.x;
  for (int i = tid; i < 128; i += 256) {
    int grow = mtile * 128 + i;
    prow[i] = (grow < cnt) ? pairs[off + grow] : -1;
  }

  int lane = tid & 63;
  int w = tid >> 6;       // wave w covers rows w*32 .. +32
  int lrow = lane & 15;
  int quad = lane >> 4;

  f32x4 acc[2][4];
#pragma unroll
  for (int i = 0; i < 2; ++i)
#pragma unroll
    for (int j = 0; j < 4; ++j) acc[i][j] = (f32x4){0.f, 0.f, 0.f, 0.f};

  const float* w2base = w2 + ((size_t)e * D_DIM + (size_t)ntile * 64) * I_DIM;

  for (int k0 = 0; k0 < I_DIM; k0 += 64) {
    __syncthreads();
    // A: 128 rows x 64 bf16, 16B chunks (8 elems): 1024 ids, 4/thread
#pragma unroll
    for (int c = 0; c < 4; ++c) {
      int id = c * 256 + tid;
      int row = id >> 3;
      int col = (id & 7) * 8;
      int grow = mtile * 128 + row;
      uint4 v = make_uint4(0u, 0u, 0u, 0u);
      if (grow < cnt)
        v = *(const uint4*)(hbuf + (size_t)(off + grow) * I_DIM + k0 + col);
      *(uint4*)&As[row * LDSP + col] = v;
    }
    // B: 64 rows x 64 fp32 -> bf16: 1024 float4 ids, 4/thread
#pragma unroll
    for (int c = 0; c < 4; ++c) {
      int id = c * 256 + tid;
      int row = id >> 4;
      int col = (id & 15) * 4;
      float4 v = *(const float4*)(w2base + (size_t)row * I_DIM + k0 + col);
      *(ushort4*)&Bs[row * LDSP + col] = f2bf4(v);
    }
    __syncthreads();
#pragma unroll
    for (int ks = 0; ks < 2; ++ks) {
      int kb = ks * 32 + quad * 8;
      bf16x8 af0 = *(const bf16x8*)&As[(w * 32 + lrow) * LDSP + kb];
      bf16x8 af1 = *(const bf16x8*)&As[(w * 32 + 16 + lrow) * LDSP + kb];
#pragma unroll
      for (int ni = 0; ni < 4; ++ni) {
        bf16x8 bfr = *(const bf16x8*)&Bs[(ni * 16 + lrow) * LDSP + kb];
        acc[0][ni] = __builtin_amdgcn_mfma_f32_16x16x32_bf16(af0, bfr, acc[0][ni], 0, 0, 0);
        acc[1][ni] = __builtin_amdgcn_mfma_f32_16x16x32_bf16(af1, bfr, acc[1][ni], 0, 0, 0);
      }
    }
  }

#pragma unroll
  for (int mi = 0; mi < 2; ++mi) {
#pragma unroll
    for (int r = 0; r < 4; ++r) {
      int lr = w * 32 + mi * 16 + quad * 4 + r;
      int grow = mtile * 128 + lr;
      if (grow < cnt) {
        int p = prow[lr];
        float* obase = out + (size_t)p * D_DIM + (size_t)ntile * 64;
#pragma unroll
        for (int ni = 0; ni < 4; ++ni)
          obase[ni * 16 + lrow] = acc[mi][ni][r];
      }
    }
  }
}

extern "C" void kernel_launch(void* const* d_in, const int* in_sizes, int n_in,
                              void* d_out, int out_size, void* d_ws, size_t ws_size,
                              hipStream_t stream) {
  const float* x  = (const float*)d_in[0];
  const float* w1 = (const float*)d_in[1];
  const float* w2 = (const float*)d_in[2];
  const float* w3 = (const float*)d_in[3];
  const int* eidx = (const int*)d_in[4];
  float* out = (float*)d_out;

  // ws layout: [0,64) meta (9 ints), [64, 64+8KB) pairs, [16384, +11.5MB) h (bf16)
  int* meta  = (int*)d_ws;
  int* pairs = (int*)((char*)d_ws + 64);
  unsigned short* hbuf = (unsigned short*)((char*)d_ws + 16384);

  sort_pairs_kernel<<<1, 256, 0, stream>>>(eidx, meta, pairs);
  dim3 g1(I_DIM / 128, (NPAIR + 127) / 128, E_NUM);   // 22 x 16 x 8
  stage1_kernel<<<g1, 256, 0, stream>>>(x, w1, w3, meta, pairs, hbuf);
  dim3 g2(D_DIM / 64, (NPAIR + 127) / 128, E_NUM);    // 16 x 16 x 8
  stage2_kernel<<<g2, 256, 0, stream>>>(hbuf, w2, meta, pairs, out);
}

// Round 2
// 441.016 us; speedup vs baseline: 1.5639x; 1.5639x over previous
//
#include <hip/hip_runtime.h>
#include <hip/hip_bf16.h>

#define E_NUM 8
#define I_DIM 2816
#define D_DIM 1024
#define T_NUM 1024
#define A_TOP 2
#define NPAIR (T_NUM * A_TOP)   // 2048
#define LDSP 72                 // fallback path pad

// ws layout (fast path)
#define HB_OFF   16384ULL
#define W1ELEMS  23068672ULL            // 8*2816*1024
#define XELEMS   1048576ULL             // 1024*1024
#define XBF_OFF  (HB_OFF + 2ULL * W1ELEMS)        // 23,085,056 (hbuf = NPAIR*I*2 = 2*W1ELEMS? no: 2048*2816*2 = 11,534,336*2)
// careful: hbuf bytes = NPAIR * I_DIM * 2 = 2048*2816*2 = 11,534,336 bytes... recompute below
#undef XBF_OFF
#define HBBYTES  ((unsigned long long)NPAIR * I_DIM * 2ULL)   // 11,534,336
#define XBF_OFF  (HB_OFF + HBBYTES)                            // 11,550,720
#define W1_OFF   (XBF_OFF + XELEMS * 2ULL)                     // 13,647,872
#define W3_OFF   (W1_OFF + W1ELEMS * 2ULL)                     // + 46,137,344
#define W2_OFF   (W3_OFF + W1ELEMS * 2ULL)
#define WS_NEED  (W2_OFF + W1ELEMS * 2ULL)

typedef __bf16 bf16x8 __attribute__((ext_vector_type(8)));
typedef float  f32x4  __attribute__((ext_vector_type(4)));

__device__ inline unsigned short f2bf(float f) {
  union { float f; unsigned u; } v; v.f = f;
  unsigned r = v.u + 0x7fffu + ((v.u >> 16) & 1u);   // RNE
  return (unsigned short)(r >> 16);
}
__device__ inline ushort4 f2bf4(float4 v) {
  ushort4 u;
  u.x = f2bf(v.x); u.y = f2bf(v.y); u.z = f2bf(v.z); u.w = f2bf(v.w);
  return u;
}

__device__ inline void gload_lds16(const unsigned short* g, unsigned short* l) {
  __builtin_amdgcn_global_load_lds((const __attribute__((address_space(1))) void*)g,
                                   (__attribute__((address_space(3))) void*)l, 16, 0, 0);
}

// ---------------- kernel 1: bucket pairs by expert ----------------
__global__ __launch_bounds__(256) void sort_pairs_kernel(
    const int* __restrict__ eidx, int* __restrict__ meta, int* __restrict__ pairs)
{
  __shared__ int cnt[E_NUM];
  __shared__ int off[E_NUM + 1];
  __shared__ int cur[E_NUM];
  int tid = threadIdx.x;
  if (tid < E_NUM) cnt[tid] = 0;
  __syncthreads();
  for (int p = tid; p < NPAIR; p += 256) atomicAdd(&cnt[eidx[p] & 7], 1);
  __syncthreads();
  if (tid == 0) {
    int s = 0;
    for (int e = 0; e < E_NUM; ++e) { off[e] = s; cur[e] = s; s += cnt[e]; }
    off[E_NUM] = s;
  }
  __syncthreads();
  for (int p = tid; p < NPAIR; p += 256) {
    int e = eidx[p] & 7;
    int pos = atomicAdd(&cur[e], 1);
    pairs[pos] = p;
  }
  __syncthreads();
  if (tid <= E_NUM) meta[tid] = off[tid];
}

// ---------------- convert fp32 -> bf16 ----------------
__global__ __launch_bounds__(256) void convert3_kernel(
    const float* __restrict__ w1, const float* __restrict__ w2,
    const float* __restrict__ w3, unsigned short* __restrict__ o1,
    unsigned short* __restrict__ o2, unsigned short* __restrict__ o3)
{
  const float* in = (blockIdx.z == 0) ? w1 : (blockIdx.z == 1) ? w2 : w3;
  unsigned short* out = (blockIdx.z == 0) ? o1 : (blockIdx.z == 1) ? o2 : o3;
  size_t i = (size_t)(blockIdx.x * 256 + threadIdx.x) * 8;
  const float4* p = (const float4*)(in + i);
  float4 a = p[0], b = p[1];
  ushort4 lo = f2bf4(a), hi = f2bf4(b);
  uint4 v;
  v.x = (unsigned)lo.x | ((unsigned)lo.y << 16);
  v.y = (unsigned)lo.z | ((unsigned)lo.w << 16);
  v.z = (unsigned)hi.x | ((unsigned)hi.y << 16);
  v.w = (unsigned)hi.z | ((unsigned)hi.w << 16);
  *(uint4*)(out + i) = v;
}

__global__ __launch_bounds__(256) void convertx_kernel(
    const float* __restrict__ in, unsigned short* __restrict__ out)
{
  size_t i = (size_t)(blockIdx.x * 256 + threadIdx.x) * 8;
  const float4* p = (const float4*)(in + i);
  float4 a = p[0], b = p[1];
  ushort4 lo = f2bf4(a), hi = f2bf4(b);
  uint4 v;
  v.x = (unsigned)lo.x | ((unsigned)lo.y << 16);
  v.y = (unsigned)lo.z | ((unsigned)lo.w << 16);
  v.z = (unsigned)hi.x | ((unsigned)hi.y << 16);
  v.w = (unsigned)hi.z | ((unsigned)hi.w << 16);
  *(uint4*)(out + i) = v;
}

// ---------------- stage1 fast: h = silu(X w1^T) * (X w3^T) ----------------
// grid (22, 16, 8), block 256 = 4 waves in 2x2 of 64x64. BK=64, async staging.
__global__ __launch_bounds__(256, 2) void stage1_fast(
    const unsigned short* __restrict__ xbf, const unsigned short* __restrict__ w1bf,
    const unsigned short* __restrict__ w3bf, const int* __restrict__ meta,
    const int* __restrict__ pairs, unsigned short* __restrict__ hbuf)
{
  int e = blockIdx.z;
  int off = meta[e];
  int cnt = meta[e + 1] - off;
  int mtile = blockIdx.y;
  if (mtile * 128 >= cnt) return;
  int ntile = blockIdx.x;

  __shared__ alignas(16) unsigned short As[128 * 64];
  __shared__ alignas(16) unsigned short B1s[128 * 64];
  __shared__ alignas(16) unsigned short B3s[128 * 64];
  __shared__ int rowtok[128];

  int tid = threadIdx.x;
  for (int i = tid; i < 128; i += 256) {
    int grow = mtile * 128 + i;
    rowtok[i] = (grow < cnt) ? (pairs[off + grow] >> 1) : 0;
  }
  __syncthreads();

  int lane = tid & 63;
  int w = tid >> 6;
  int wm = w >> 1, wn = w & 1;
  int lrow = lane & 15;
  int quad = lane >> 4;

  // staging: wave w covers rows 32w..32w+31, 4 issues of 8 rows x 8 chunks
  int srow = lane >> 3;                 // 0..7
  int schunk = (lane & 7) ^ srow;       // xor-swizzled chunk
  size_t wbase = ((size_t)e * I_DIM + (size_t)ntile * 128) * D_DIM;
  size_t aoff[4], woff[4];
#pragma unroll
  for (int j = 0; j < 4; ++j) {
    int row = 32 * w + 8 * j + srow;
    aoff[j] = (size_t)rowtok[row] * D_DIM + schunk * 8;
    woff[j] = wbase + (size_t)row * D_DIM + schunk * 8;
  }

  f32x4 acc1[4][4], acc3[4][4];
#pragma unroll
  for (int i = 0; i < 4; ++i)
#pragma unroll
    for (int j = 0; j < 4; ++j) {
      acc1[i][j] = (f32x4){0.f, 0.f, 0.f, 0.f};
      acc3[i][j] = (f32x4){0.f, 0.f, 0.f, 0.f};
    }

  for (int k0 = 0; k0 < D_DIM; k0 += 64) {
    __syncthreads();
#pragma unroll
    for (int j = 0; j < 4; ++j) {
      int ldsrow = (32 * w + 8 * j) * 64;
      gload_lds16(xbf + aoff[j] + k0, &As[ldsrow]);
      gload_lds16(w1bf + woff[j] + k0, &B1s[ldsrow]);
      gload_lds16(w3bf + woff[j] + k0, &B3s[ldsrow]);
    }
    __syncthreads();
#pragma unroll
    for (int ks = 0; ks < 2; ++ks) {
      int sw = ((ks * 4 + quad) ^ (lrow & 7)) * 8;   // swizzled chunk offset (elems)
      bf16x8 af[4];
#pragma unroll
      for (int mi = 0; mi < 4; ++mi)
        af[mi] = *(const bf16x8*)&As[(wm * 64 + mi * 16 + lrow) * 64 + sw];
#pragma unroll
      for (int ni = 0; ni < 4; ++ni) {
        bf16x8 b1 = *(const bf16x8*)&B1s[(wn * 64 + ni * 16 + lrow) * 64 + sw];
#pragma unroll
        for (int mi = 0; mi < 4; ++mi)
          acc1[mi][ni] = __builtin_amdgcn_mfma_f32_16x16x32_bf16(af[mi], b1, acc1[mi][ni], 0, 0, 0);
        bf16x8 b3 = *(const bf16x8*)&B3s[(wn * 64 + ni * 16 + lrow) * 64 + sw];
#pragma unroll
        for (int mi = 0; mi < 4; ++mi)
          acc3[mi][ni] = __builtin_amdgcn_mfma_f32_16x16x32_bf16(af[mi], b3, acc3[mi][ni], 0, 0, 0);
      }
    }
  }

#pragma unroll
  for (int mi = 0; mi < 4; ++mi) {
#pragma unroll
    for (int r = 0; r < 4; ++r) {
      int lr = wm * 64 + mi * 16 + quad * 4 + r;
      int grow = mtile * 128 + lr;
      if (grow < cnt) {
        size_t base = (size_t)(off + grow) * I_DIM + (size_t)ntile * 128 + wn * 64;
#pragma unroll
        for (int ni = 0; ni < 4; ++ni) {
          float v1 = acc1[mi][ni][r];
          float v3 = acc3[mi][ni][r];
          float hv = (v1 / (1.f + __expf(-v1))) * v3;
          hbuf[base + ni * 16 + lrow] = f2bf(hv);
        }
      }
    }
  }
}

// ---------------- stage2 fast: out = h w2^T, scatter ----------------
// grid (16, 16, 8), block 256 = 4 waves each 32 rows x 64 cols. BK=64.
__global__ __launch_bounds__(256, 2) void stage2_fast(
    const unsigned short* __restrict__ hbuf, const unsigned short* __restrict__ w2bf,
    const int* __restrict__ meta, const int* __restrict__ pairs,
    float* __restrict__ out)
{
  int e = blockIdx.z;
  int off = meta[e];
  int cnt = meta[e + 1] - off;
  int mtile = blockIdx.y;
  if (mtile * 128 >= cnt) return;
  int ntile = blockIdx.x;

  __shared__ alignas(16) unsigned short As[128 * 64];
  __shared__ alignas(16) unsigned short Bs[64 * 64];
  __shared__ int prow[128];

  int tid = threadIdx.x;
  for (int i = tid; i < 128; i += 256) {
    int grow = mtile * 128 + i;
    prow[i] = (grow < cnt) ? pairs[off + grow] : -1;
  }
  __syncthreads();

  int lane = tid & 63;
  int w = tid >> 6;
  int lrow = lane & 15;
  int quad = lane >> 4;

  int srow = lane >> 3;
  int schunk = (lane & 7) ^ srow;
  size_t aoff[4], boff[2];
#pragma unroll
  for (int j = 0; j < 4; ++j) {
    int gr = off + mtile * 128 + 32 * w + 8 * j + srow;
    if (gr > NPAIR - 1) gr = NPAIR - 1;
    aoff[j] = (size_t)gr * I_DIM + schunk * 8;
  }
#pragma unroll
  for (int j = 0; j < 2; ++j) {
    int row = 16 * w + 8 * j + srow;
    boff[j] = ((size_t)e * D_DIM + (size_t)ntile * 64 + row) * I_DIM + schunk * 8;
  }

  f32x4 acc[2][4];
#pragma unroll
  for (int i = 0; i < 2; ++i)
#pragma unroll
    for (int j = 0; j < 4; ++j) acc[i][j] = (f32x4){0.f, 0.f, 0.f, 0.f};

  for (int k0 = 0; k0 < I_DIM; k0 += 64) {
    __syncthreads();
#pragma unroll
    for (int j = 0; j < 4; ++j)
      gload_lds16(hbuf + aoff[j] + k0, &As[(32 * w + 8 * j) * 64]);
#pragma unroll
    for (int j = 0; j < 2; ++j)
      gload_lds16(w2bf + boff[j] + k0, &Bs[(16 * w + 8 * j) * 64]);
    __syncthreads();
#pragma unroll
    for (int ks = 0; ks < 2; ++ks) {
      int sw = ((ks * 4 + quad) ^ (lrow & 7)) * 8;
      bf16x8 af0 = *(const bf16x8*)&As[(w * 32 + lrow) * 64 + sw];
      bf16x8 af1 = *(const bf16x8*)&As[(w * 32 + 16 + lrow) * 64 + sw];
#pragma unroll
      for (int ni = 0; ni < 4; ++ni) {
        bf16x8 bfr = *(const bf16x8*)&Bs[(ni * 16 + lrow) * 64 + sw];
        acc[0][ni] = __builtin_amdgcn_mfma_f32_16x16x32_bf16(af0, bfr, acc[0][ni], 0, 0, 0);
        acc[1][ni] = __builtin_amdgcn_mfma_f32_16x16x32_bf16(af1, bfr, acc[1][ni], 0, 0, 0);
      }
    }
  }

#pragma unroll
  for (int mi = 0; mi < 2; ++mi) {
#pragma unroll
    for (int r = 0; r < 4; ++r) {
      int lr = w * 32 + mi * 16 + quad * 4 + r;
      int grow = mtile * 128 + lr;
      if (grow < cnt) {
        int p = prow[lr];
        float* obase = out + (size_t)p * D_DIM + (size_t)ntile * 64;
#pragma unroll
        for (int ni = 0; ni < 4; ++ni)
          obase[ni * 16 + lrow] = acc[mi][ni][r];
      }
    }
  }
}

// ======================= fallback (round-1, known-correct) =======================
__global__ __launch_bounds__(256) void stage1_kernel(
    const float* __restrict__ x, const float* __restrict__ w1,
    const float* __restrict__ w3, const int* __restrict__ meta,
    const int* __restrict__ pairs, unsigned short* __restrict__ hbuf)
{
  int e = blockIdx.z;
  int off = meta[e];
  int cnt = meta[e + 1] - off;
  int mtile = blockIdx.y;
  if (mtile * 128 >= cnt) return;
  int ntile = blockIdx.x;

  __shared__ alignas(16) unsigned short As[128 * LDSP];
  __shared__ alignas(16) unsigned short B1s[128 * LDSP];
  __shared__ alignas(16) unsigned short B3s[128 * LDSP];
  __shared__ int rowtok[128];

  int tid = threadIdx.x;
  for (int i = tid; i < 128; i += 256) {
    int grow = mtile * 128 + i;
    rowtok[i] = (grow < cnt) ? (pairs[off + grow] >> 1) : -1;
  }

  int lane = tid & 63;
  int w = tid >> 6;
  int wm = w >> 1, wn = w & 1;
  int lrow = lane & 15;
  int quad = lane >> 4;

  f32x4 acc1[4][4], acc3[4][4];
#pragma unroll
  for (int i = 0; i < 4; ++i)
#pragma unroll
    for (int j = 0; j < 4; ++j) {
      acc1[i][j] = (f32x4){0.f, 0.f, 0.f, 0.f};
      acc3[i][j] = (f32x4){0.f, 0.f, 0.f, 0.f};
    }

  const float* w1base = w1 + ((size_t)e * I_DIM + (size_t)ntile * 128) * D_DIM;
  const float* w3base = w3 + ((size_t)e * I_DIM + (size_t)ntile * 128) * D_DIM;

  for (int k0 = 0; k0 < D_DIM; k0 += 64) {
    __syncthreads();
#pragma unroll
    for (int c = 0; c < 8; ++c) {
      int id = c * 256 + tid;
      int row = id >> 4;
      int col = (id & 15) * 4;
      int tok = rowtok[row];
      float4 va = make_float4(0.f, 0.f, 0.f, 0.f);
      if (tok >= 0) va = *(const float4*)(x + (size_t)tok * D_DIM + k0 + col);
      *(ushort4*)&As[row * LDSP + col] = f2bf4(va);
      float4 v1 = *(const float4*)(w1base + (size_t)row * D_DIM + k0 + col);
      *(ushort4*)&B1s[row * LDSP + col] = f2bf4(v1);
      float4 v3 = *(const float4*)(w3base + (size_t)row * D_DIM + k0 + col);
      *(ushort4*)&B3s[row * LDSP + col] = f2bf4(v3);
    }
    __syncthreads();
#pragma unroll
    for (int ks = 0; ks < 2; ++ks) {
      int kb = ks * 32 + quad * 8;
      bf16x8 af[4];
#pragma unroll
      for (int mi = 0; mi < 4; ++mi)
        af[mi] = *(const bf16x8*)&As[(wm * 64 + mi * 16 + lrow) * LDSP + kb];
#pragma unroll
      for (int ni = 0; ni < 4; ++ni) {
        bf16x8 b1 = *(const bf16x8*)&B1s[(wn * 64 + ni * 16 + lrow) * LDSP + kb];
#pragma unroll
        for (int mi = 0; mi < 4; ++mi)
          acc1[mi][ni] = __builtin_amdgcn_mfma_f32_16x16x32_bf16(af[mi], b1, acc1[mi][ni], 0, 0, 0);
        bf16x8 b3 = *(const bf16x8*)&B3s[(wn * 64 + ni * 16 + lrow) * LDSP + kb];
#pragma unroll
        for (int mi = 0; mi < 4; ++mi)
          acc3[mi][ni] = __builtin_amdgcn_mfma_f32_16x16x32_bf16(af[mi], b3, acc3[mi][ni], 0, 0, 0);
      }
    }
  }

#pragma unroll
  for (int mi = 0; mi < 4; ++mi) {
#pragma unroll
    for (int r = 0; r < 4; ++r) {
      int lr = wm * 64 + mi * 16 + quad * 4 + r;
      int grow = mtile * 128 + lr;
      if (grow < cnt) {
        size_t base = (size_t)(off + grow) * I_DIM + (size_t)ntile * 128 + wn * 64;
#pragma unroll
        for (int ni = 0; ni < 4; ++ni) {
          float v1 = acc1[mi][ni][r];
          float v3 = acc3[mi][ni][r];
          float hv = (v1 / (1.f + __expf(-v1))) * v3;
          hbuf[base + ni * 16 + lrow] = f2bf(hv);
        }
      }
    }
  }
}

__global__ __launch_bounds__(256) void stage2_kernel(
    const unsigned short* __restrict__ hbuf, const float* __restrict__ w2,
    const int* __restrict__ meta, const int* __restrict__ pairs,
    float* __restrict__ out)
{
  int e = blockIdx.z;
  int off = meta[e];
  int cnt = meta[e + 1] - off;
  int mtile = blockIdx.y;
  if (mtile * 128 >= cnt) return;
  int ntile = blockIdx.x;

  __shared__ alignas(16) unsigned short As[128 * LDSP];
  __shared__ alignas(16) unsigned short Bs[64 * LDSP];
  __shared__ int prow[128];

  int tid = threadIdx.x;
  for (int i = tid; i < 128; i += 256) {
    int grow = mtile * 128 + i;
    prow[i] = (grow < cnt) ? pairs[off + grow] : -1;
  }

  int lane = tid & 63;
  int w = tid >> 6;
  int lrow = lane & 15;
  int quad = lane >> 4;

  f32x4 acc[2][4];
#pragma unroll
  for (int i = 0; i < 2; ++i)
#pragma unroll
    for (int j = 0; j < 4; ++j) acc[i][j] = (f32x4){0.f, 0.f, 0.f, 0.f};

  const float* w2base = w2 + ((size_t)e * D_DIM + (size_t)ntile * 64) * I_DIM;

  for (int k0 = 0; k0 < I_DIM; k0 += 64) {
    __syncthreads();
#pragma unroll
    for (int c = 0; c < 4; ++c) {
      int id = c * 256 + tid;
      int row = id >> 3;
      int col = (id & 7) * 8;
      int grow = mtile * 128 + row;
      uint4 v = make_uint4(0u, 0u, 0u, 0u);
      if (grow < cnt)
        v = *(const uint4*)(hbuf + (size_t)(off + grow) * I_DIM + k0 + col);
      *(uint4*)&As[row * LDSP + col] = v;
    }
#pragma unroll
    for (int c = 0; c < 4; ++c) {
      int id = c * 256 + tid;
      int row = id >> 4;
      int col = (id & 15) * 4;
      float4 v = *(const float4*)(w2base + (size_t)row * I_DIM + k0 + col);
      *(ushort4*)&Bs[row * LDSP + col] = f2bf4(v);
    }
    __syncthreads();
#pragma unroll
    for (int ks = 0; ks < 2; ++ks) {
      int kb = ks * 32 + quad * 8;
      bf16x8 af0 = *(const bf16x8*)&As[(w * 32 + lrow) * LDSP + kb];
      bf16x8 af1 = *(const bf16x8*)&As[(w * 32 + 16 + lrow) * LDSP + kb];
#pragma unroll
      for (int ni = 0; ni < 4; ++ni) {
        bf16x8 bfr = *(const bf16x8*)&Bs[(ni * 16 + lrow) * LDSP + kb];
        acc[0][ni] = __builtin_amdgcn_mfma_f32_16x16x32_bf16(af0, bfr, acc[0][ni], 0, 0, 0);
        acc[1][ni] = __builtin_amdgcn_mfma_f32_16x16x32_bf16(af1, bfr, acc[1][ni], 0, 0, 0);
      }
    }
  }

#pragma unroll
  for (int mi = 0; mi < 2; ++mi) {
#pragma unroll
    for (int r = 0; r < 4; ++r) {
      int lr = w * 32 + mi * 16 + quad * 4 + r;
      int grow = mtile * 128 + lr;
      if (grow < cnt) {
        int p = prow[lr];
        float* obase = out + (size_t)p * D_DIM + (size_t)ntile * 64;
#pragma unroll
        for (int ni = 0; ni < 4; ++ni)
          obase[ni * 16 + lrow] = acc[mi][ni][r];
      }
    }
  }
}

extern "C" void kernel_launch(void* const* d_in, const int* in_sizes, int n_in,
                              void* d_out, int out_size, void* d_ws, size_t ws_size,
                              hipStream_t stream) {
  const float* x  = (const float*)d_in[0];
  const float* w1 = (const float*)d_in[1];
  const float* w2 = (const float*)d_in[2];
  const float* w3 = (const float*)d_in[3];
  const int* eidx = (const int*)d_in[4];
  float* out = (float*)d_out;

  int* meta  = (int*)d_ws;
  int* pairs = (int*)((char*)d_ws + 64);
  unsigned short* hbuf = (unsigned short*)((char*)d_ws + HB_OFF);

  sort_pairs_kernel<<<1, 256, 0, stream>>>(eidx, meta, pairs);

  if (ws_size >= WS_NEED) {
    unsigned short* xbf  = (unsigned short*)((char*)d_ws + XBF_OFF);
    unsigned short* w1bf = (unsigned short*)((char*)d_ws + W1_OFF);
    unsigned short* w3bf = (unsigned short*)((char*)d_ws + W3_OFF);
    unsigned short* w2bf = (unsigned short*)((char*)d_ws + W2_OFF);

    dim3 gc(W1ELEMS / 8 / 256, 1, 3);      // 11264 x 1 x 3
    convert3_kernel<<<gc, 256, 0, stream>>>(w1, w2, w3, w1bf, w2bf, w3bf);
    convertx_kernel<<<XELEMS / 8 / 256, 256, 0, stream>>>(x, (unsigned short*)((char*)d_ws + XBF_OFF));

    dim3 g1(I_DIM / 128, (NPAIR + 127) / 128, E_NUM);   // 22 x 16 x 8
    stage1_fast<<<g1, 256, 0, stream>>>(xbf, w1bf, w3bf, meta, pairs, hbuf);
    dim3 g2(D_DIM / 64, (NPAIR + 127) / 128, E_NUM);    // 16 x 16 x 8
    stage2_fast<<<g2, 256, 0, stream>>>(hbuf, w2bf, meta, pairs, out);
  } else {
    dim3 g1(I_DIM / 128, (NPAIR + 127) / 128, E_NUM);
    stage1_kernel<<<g1, 256, 0, stream>>>(x, w1, w3, meta, pairs, hbuf);
    dim3 g2(D_DIM / 64, (NPAIR + 127) / 128, E_NUM);
    stage2_kernel<<<g2, 256, 0, stream>>>(hbuf, w2, meta, pairs, out);
  }
}

// Round 3
// 384.816 us; speedup vs baseline: 1.7924x; 1.1460x over previous
//
#include <hip/hip_runtime.h>
#include <hip/hip_bf16.h>

#define E_NUM 8
#define I_DIM 2816
#define D_DIM 1024
#define T_NUM 1024
#define A_TOP 2
#define NPAIR (T_NUM * A_TOP)   // 2048
#define PADROWS 3072            // worst-case 128-padded rows
#define MT_MAX (PADROWS / 128)  // 24

// ws layout: [0,64) meta (9 ints), [64,+PADROWS*4) pairs, hbuf @16384, xbf after
#define HB_OFF    16384ULL
#define HB_BYTES  ((unsigned long long)PADROWS * I_DIM * 2ULL)   // 17,301,504
#define XBF_OFF   (HB_OFF + HB_BYTES)
#define XBF_BYTES ((unsigned long long)T_NUM * D_DIM * 2ULL)     // 2 MB
#define WS_NEED   (XBF_OFF + XBF_BYTES)

typedef __bf16 bf16x8 __attribute__((ext_vector_type(8)));
typedef float  f32x4  __attribute__((ext_vector_type(4)));

__device__ inline unsigned short f2bf(float f) {
  union { float f; unsigned u; } v; v.f = f;
  unsigned r = v.u + 0x7fffu + ((v.u >> 16) & 1u);   // RNE
  return (unsigned short)(r >> 16);
}
__device__ inline uint4 pack8(float4 a, float4 b) {
  uint4 v;
  v.x = (unsigned)f2bf(a.x) | ((unsigned)f2bf(a.y) << 16);
  v.y = (unsigned)f2bf(a.z) | ((unsigned)f2bf(a.w) << 16);
  v.z = (unsigned)f2bf(b.x) | ((unsigned)f2bf(b.y) << 16);
  v.w = (unsigned)f2bf(b.z) | ((unsigned)f2bf(b.w) << 16);
  return v;
}
__device__ inline void gload_lds16(const unsigned short* g, unsigned short* l) {
  __builtin_amdgcn_global_load_lds((const __attribute__((address_space(1))) void*)g,
                                   (__attribute__((address_space(3))) void*)l, 16, 0, 0);
}

// ---------------- kernel 1: bucket pairs by expert, 128-padded segments -------
__global__ __launch_bounds__(256) void sort_pairs_kernel(
    const int* __restrict__ eidx, int* __restrict__ meta, int* __restrict__ pairs)
{
  __shared__ int cnt[E_NUM];
  __shared__ int pstart[E_NUM + 1];
  __shared__ int cur[E_NUM];
  int tid = threadIdx.x;
  if (tid < E_NUM) cnt[tid] = 0;
  __syncthreads();
  for (int p = tid; p < NPAIR; p += 256) atomicAdd(&cnt[eidx[p] & 7], 1);
  for (int i = tid; i < PADROWS; i += 256) pairs[i] = -1;
  __syncthreads();
  if (tid == 0) {
    int s = 0;
    for (int e = 0; e < E_NUM; ++e) {
      pstart[e] = s; cur[e] = s;
      s += ((cnt[e] + 127) / 128) * 128;
    }
    pstart[E_NUM] = s;
  }
  __syncthreads();
  for (int p = tid; p < NPAIR; p += 256) {
    int e = eidx[p] & 7;
    int pos = atomicAdd(&cur[e], 1);
    pairs[pos] = p;
  }
  __syncthreads();
  if (tid <= E_NUM) meta[tid] = pstart[tid];
}

// ---------------- x: fp32 -> bf16 (4 MB, trivial) ----------------
__global__ __launch_bounds__(256) void convertx_kernel(
    const float* __restrict__ in, unsigned short* __restrict__ out)
{
  size_t i = (size_t)(blockIdx.x * 256 + threadIdx.x) * 8;
  const float4* p = (const float4*)(in + i);
  *(uint4*)(out + i) = pack8(p[0], p[1]);
}

// ---------------- stage1: h = silu(X w1^T) * (X w3^T), fused fp32->bf16 -------
// grid (22, 24), block 256 = 4 waves (2x2 of 64x64). BK=32, reg-prefetch dbuf.
__global__ __launch_bounds__(256, 2) void stage1_fused(
    const unsigned short* __restrict__ xbf, const float* __restrict__ w1,
    const float* __restrict__ w3, const int* __restrict__ meta,
    const int* __restrict__ pairs, unsigned short* __restrict__ hbuf)
{
  int mtile = blockIdx.y;
  int ptotal = meta[E_NUM];
  if (mtile * 128 >= ptotal) return;
  int e = 0;
  while (meta[e + 1] <= mtile * 128) ++e;
  int ntile = blockIdx.x;

  __shared__ alignas(16) unsigned short As[2][128 * 32];
  __shared__ alignas(16) unsigned short B1s[2][128 * 32];
  __shared__ alignas(16) unsigned short B3s[2][128 * 32];
  __shared__ int rowtok[128];

  int tid = threadIdx.x;
  for (int i = tid; i < 128; i += 256) {
    int p = pairs[mtile * 128 + i];
    rowtok[i] = (p >= 0) ? (p >> 1) : -1;
  }
  __syncthreads();

  int lane = tid & 63;
  int w = tid >> 6;
  int wm = w >> 1, wn = w & 1;
  int lrow = lane & 15, quad = lane >> 4;

  // staging: wave w handles chunks 2w, 2w+1 (chunk = 16 rows x 32 cols)
  int lr4 = lane >> 2;          // row within chunk 0..15
  int lc  = (lane & 3) * 8;     // col base 0/8/16/24
  int c0 = 2 * w;
  size_t aoff[2];
  const float* wb1[2];
  const float* wb3[2];
#pragma unroll
  for (int j = 0; j < 2; ++j) {
    int c = c0 + j;
    int r = c * 16 + lr4;
    int tok = rowtok[r]; if (tok < 0) tok = 0;
    aoff[j] = (size_t)tok * D_DIM + lc;
    int irow = ntile * 128 + r;
    wb1[j] = w1 + ((size_t)e * I_DIM + irow) * D_DIM + lc;
    wb3[j] = w3 + ((size_t)e * I_DIM + irow) * D_DIM + lc;
  }

  f32x4 acc1[4][4], acc3[4][4];
#pragma unroll
  for (int i = 0; i < 4; ++i)
#pragma unroll
    for (int j = 0; j < 4; ++j) {
      acc1[i][j] = (f32x4){0.f, 0.f, 0.f, 0.f};
      acc3[i][j] = (f32x4){0.f, 0.f, 0.f, 0.f};
    }

  // prologue: K-tile 0
  float4 r1[2][2], r3[2][2];
#pragma unroll
  for (int j = 0; j < 2; ++j) {
    r1[j][0] = *(const float4*)(wb1[j]);
    r1[j][1] = *(const float4*)(wb1[j] + 4);
    r3[j][0] = *(const float4*)(wb3[j]);
    r3[j][1] = *(const float4*)(wb3[j] + 4);
    gload_lds16(xbf + aoff[j], &As[0][(c0 + j) * 512]);
  }
#pragma unroll
  for (int j = 0; j < 2; ++j) {
    *(uint4*)&B1s[0][(c0 + j) * 512 + lane * 8] = pack8(r1[j][0], r1[j][1]);
    *(uint4*)&B3s[0][(c0 + j) * 512 + lane * 8] = pack8(r3[j][0], r3[j][1]);
  }

  const int KT = D_DIM / 32;    // 32
  for (int k = 0; k < KT; ++k) {
    __syncthreads();
    int kk = k & 1;
    if (k + 1 < KT) {
      int kn = (k + 1) * 32;
#pragma unroll
      for (int j = 0; j < 2; ++j) {
        r1[j][0] = *(const float4*)(wb1[j] + kn);
        r1[j][1] = *(const float4*)(wb1[j] + kn + 4);
        r3[j][0] = *(const float4*)(wb3[j] + kn);
        r3[j][1] = *(const float4*)(wb3[j] + kn + 4);
        gload_lds16(xbf + aoff[j] + kn, &As[kk ^ 1][(c0 + j) * 512]);
      }
    }
    bf16x8 af[4];
#pragma unroll
    for (int mi = 0; mi < 4; ++mi)
      af[mi] = *(const bf16x8*)&As[kk][(wm * 64 + mi * 16 + lrow) * 32 + quad * 8];
#pragma unroll
    for (int ni = 0; ni < 4; ++ni) {
      bf16x8 b1 = *(const bf16x8*)&B1s[kk][(wn * 64 + ni * 16 + lrow) * 32 + quad * 8];
#pragma unroll
      for (int mi = 0; mi < 4; ++mi)
        acc1[mi][ni] = __builtin_amdgcn_mfma_f32_16x16x32_bf16(af[mi], b1, acc1[mi][ni], 0, 0, 0);
      bf16x8 b3 = *(const bf16x8*)&B3s[kk][(wn * 64 + ni * 16 + lrow) * 32 + quad * 8];
#pragma unroll
      for (int mi = 0; mi < 4; ++mi)
        acc3[mi][ni] = __builtin_amdgcn_mfma_f32_16x16x32_bf16(af[mi], b3, acc3[mi][ni], 0, 0, 0);
    }
    if (k + 1 < KT) {
#pragma unroll
      for (int j = 0; j < 2; ++j) {
        *(uint4*)&B1s[kk ^ 1][(c0 + j) * 512 + lane * 8] = pack8(r1[j][0], r1[j][1]);
        *(uint4*)&B3s[kk ^ 1][(c0 + j) * 512 + lane * 8] = pack8(r3[j][0], r3[j][1]);
      }
    }
  }

  // epilogue: h = silu(a1)*a3 -> bf16 at padded row index
#pragma unroll
  for (int mi = 0; mi < 4; ++mi) {
#pragma unroll
    for (int r = 0; r < 4; ++r) {
      int lr = wm * 64 + mi * 16 + quad * 4 + r;
      if (rowtok[lr] >= 0) {
        size_t base = (size_t)(mtile * 128 + lr) * I_DIM + (size_t)ntile * 128 + wn * 64;
#pragma unroll
        for (int ni = 0; ni < 4; ++ni) {
          float v1 = acc1[mi][ni][r];
          float v3 = acc3[mi][ni][r];
          float hv = (v1 / (1.f + __expf(-v1))) * v3;
          hbuf[base + ni * 16 + lrow] = f2bf(hv);
        }
      }
    }
  }
}

// ---------------- stage2: out = h w2^T, fused fp32->bf16, scatter -------------
// grid (16, 24), block 256 = 4 waves each 32 rows x 64 cols. BK=32.
__global__ __launch_bounds__(256, 4) void stage2_fused(
    const unsigned short* __restrict__ hbuf, const float* __restrict__ w2,
    const int* __restrict__ meta, const int* __restrict__ pairs,
    float* __restrict__ out)
{
  int mtile = blockIdx.y;
  int ptotal = meta[E_NUM];
  if (mtile * 128 >= ptotal) return;
  int e = 0;
  while (meta[e + 1] <= mtile * 128) ++e;
  int ntile = blockIdx.x;

  __shared__ alignas(16) unsigned short As[2][128 * 32];
  __shared__ alignas(16) unsigned short Bs[2][64 * 32];
  __shared__ int prow[128];

  int tid = threadIdx.x;
  for (int i = tid; i < 128; i += 256) {
    int grow = mtile * 128 + i;
    prow[i] = pairs[grow];
  }
  __syncthreads();

  int lane = tid & 63;
  int w = tid >> 6;
  int lrow = lane & 15, quad = lane >> 4;
  int lr4 = lane >> 2;
  int lc  = (lane & 3) * 8;
  int c0 = 2 * w;

  size_t aoff[2];
#pragma unroll
  for (int j = 0; j < 2; ++j)
    aoff[j] = (size_t)(mtile * 128 + (c0 + j) * 16 + lr4) * I_DIM + lc;
  const float* wb2 = w2 + ((size_t)e * D_DIM + ntile * 64 + w * 16 + lr4) * I_DIM + lc;

  f32x4 acc[2][4];
#pragma unroll
  for (int i = 0; i < 2; ++i)
#pragma unroll
    for (int j = 0; j < 4; ++j) acc[i][j] = (f32x4){0.f, 0.f, 0.f, 0.f};

  // prologue: K-tile 0
  float4 rb[2];
  rb[0] = *(const float4*)(wb2);
  rb[1] = *(const float4*)(wb2 + 4);
#pragma unroll
  for (int j = 0; j < 2; ++j)
    gload_lds16(hbuf + aoff[j], &As[0][(c0 + j) * 512]);
  *(uint4*)&Bs[0][w * 512 + lane * 8] = pack8(rb[0], rb[1]);

  const int KT = I_DIM / 32;   // 88
  for (int k = 0; k < KT; ++k) {
    __syncthreads();
    int kk = k & 1;
    if (k + 1 < KT) {
      int kn = (k + 1) * 32;
      rb[0] = *(const float4*)(wb2 + kn);
      rb[1] = *(const float4*)(wb2 + kn + 4);
#pragma unroll
      for (int j = 0; j < 2; ++j)
        gload_lds16(hbuf + aoff[j] + kn, &As[kk ^ 1][(c0 + j) * 512]);
    }
    bf16x8 af0 = *(const bf16x8*)&As[kk][(w * 32 + lrow) * 32 + quad * 8];
    bf16x8 af1 = *(const bf16x8*)&As[kk][(w * 32 + 16 + lrow) * 32 + quad * 8];
#pragma unroll
    for (int ni = 0; ni < 4; ++ni) {
      bf16x8 bfr = *(const bf16x8*)&Bs[kk][(ni * 16 + lrow) * 32 + quad * 8];
      acc[0][ni] = __builtin_amdgcn_mfma_f32_16x16x32_bf16(af0, bfr, acc[0][ni], 0, 0, 0);
      acc[1][ni] = __builtin_amdgcn_mfma_f32_16x16x32_bf16(af1, bfr, acc[1][ni], 0, 0, 0);
    }
    if (k + 1 < KT)
      *(uint4*)&Bs[kk ^ 1][w * 512 + lane * 8] = pack8(rb[0], rb[1]);
  }

#pragma unroll
  for (int mi = 0; mi < 2; ++mi) {
#pragma unroll
    for (int r = 0; r < 4; ++r) {
      int lr = w * 32 + mi * 16 + quad * 4 + r;
      int p = prow[lr];
      if (p >= 0) {
        float* obase = out + (size_t)p * D_DIM + (size_t)ntile * 64;
#pragma unroll
        for (int ni = 0; ni < 4; ++ni)
          obase[ni * 16 + lrow] = acc[mi][ni][r];
      }
    }
  }
}

extern "C" void kernel_launch(void* const* d_in, const int* in_sizes, int n_in,
                              void* d_out, int out_size, void* d_ws, size_t ws_size,
                              hipStream_t stream) {
  const float* x  = (const float*)d_in[0];
  const float* w1 = (const float*)d_in[1];
  const float* w2 = (const float*)d_in[2];
  const float* w3 = (const float*)d_in[3];
  const int* eidx = (const int*)d_in[4];
  float* out = (float*)d_out;

  int* meta  = (int*)d_ws;
  int* pairs = (int*)((char*)d_ws + 64);
  unsigned short* hbuf = (unsigned short*)((char*)d_ws + HB_OFF);
  unsigned short* xbf  = (unsigned short*)((char*)d_ws + XBF_OFF);

  sort_pairs_kernel<<<1, 256, 0, stream>>>(eidx, meta, pairs);
  convertx_kernel<<<(T_NUM * D_DIM) / 8 / 256, 256, 0, stream>>>(x, xbf);

  dim3 g1(I_DIM / 128, MT_MAX);   // 22 x 24
  stage1_fused<<<g1, 256, 0, stream>>>(xbf, w1, w3, meta, pairs, hbuf);
  dim3 g2(D_DIM / 64, MT_MAX);    // 16 x 24
  stage2_fused<<<g2, 256, 0, stream>>>(hbuf, w2, meta, pairs, out);
}

// Round 4
// 348.205 us; speedup vs baseline: 1.9808x; 1.1051x over previous
//
#include <hip/hip_runtime.h>
#include <hip/hip_bf16.h>

#define E_NUM 8
#define I_DIM 2816
#define D_DIM 1024
#define T_NUM 1024
#define A_TOP 2
#define NPAIR (T_NUM * A_TOP)   // 2048
#define PADROWS 3072            // worst-case 128-padded rows
#define MT_MAX (PADROWS / 128)  // 24
#define KSPLIT 4
#define KCHUNK (I_DIM / KSPLIT) // 704
#define KT2 (KCHUNK / 32)       // 22

// ws layout: [0,64) meta, [64,+PADROWS*4) pairs, hbuf @16384, xbf after
#define HB_OFF    16384ULL
#define HB_BYTES  ((unsigned long long)PADROWS * I_DIM * 2ULL)
#define XBF_OFF   (HB_OFF + HB_BYTES)

typedef __bf16 bf16x8 __attribute__((ext_vector_type(8)));
typedef float  f32x4  __attribute__((ext_vector_type(4)));

__device__ inline unsigned short f2bf(float f) {
  union { float f; unsigned u; } v; v.f = f;
  unsigned r = v.u + 0x7fffu + ((v.u >> 16) & 1u);   // RNE
  return (unsigned short)(r >> 16);
}
__device__ inline uint4 pack8(float4 a, float4 b) {
  uint4 v;
  v.x = (unsigned)f2bf(a.x) | ((unsigned)f2bf(a.y) << 16);
  v.y = (unsigned)f2bf(a.z) | ((unsigned)f2bf(a.w) << 16);
  v.z = (unsigned)f2bf(b.x) | ((unsigned)f2bf(b.y) << 16);
  v.w = (unsigned)f2bf(b.z) | ((unsigned)f2bf(b.w) << 16);
  return v;
}
__device__ inline void gload_lds16(const unsigned short* g, unsigned short* l) {
  __builtin_amdgcn_global_load_lds((const __attribute__((address_space(1))) void*)g,
                                   (__attribute__((address_space(3))) void*)l, 16, 0, 0);
}

// ---------------- kernel 1: bucket pairs by expert, 128-padded segments -------
__global__ __launch_bounds__(256) void sort_pairs_kernel(
    const int* __restrict__ eidx, int* __restrict__ meta, int* __restrict__ pairs)
{
  __shared__ int cnt[E_NUM];
  __shared__ int pstart[E_NUM + 1];
  __shared__ int cur[E_NUM];
  int tid = threadIdx.x;
  if (tid < E_NUM) cnt[tid] = 0;
  __syncthreads();
  for (int p = tid; p < NPAIR; p += 256) atomicAdd(&cnt[eidx[p] & 7], 1);
  for (int i = tid; i < PADROWS; i += 256) pairs[i] = -1;
  __syncthreads();
  if (tid == 0) {
    int s = 0;
    for (int e = 0; e < E_NUM; ++e) {
      pstart[e] = s; cur[e] = s;
      s += ((cnt[e] + 127) / 128) * 128;
    }
    pstart[E_NUM] = s;
  }
  __syncthreads();
  for (int p = tid; p < NPAIR; p += 256) {
    int e = eidx[p] & 7;
    int pos = atomicAdd(&cur[e], 1);
    pairs[pos] = p;
  }
  __syncthreads();
  if (tid <= E_NUM) meta[tid] = pstart[tid];
}

// ---------------- x: fp32 -> bf16 ----------------
__global__ __launch_bounds__(256) void convertx_kernel(
    const float* __restrict__ in, unsigned short* __restrict__ out)
{
  size_t i = (size_t)(blockIdx.x * 256 + threadIdx.x) * 8;
  const float4* p = (const float4*)(in + i);
  *(uint4*)(out + i) = pack8(p[0], p[1]);
}

// ---------------- stage1: h = silu(X w1^T) * (X w3^T) -------------------------
// grid (44, 24), block 256 = 4 waves (2x2), wave-tile 64x32. BK=32 dbuf.
__global__ __launch_bounds__(256, 3) void stage1_v4(
    const unsigned short* __restrict__ xbf, const float* __restrict__ w1,
    const float* __restrict__ w3, const int* __restrict__ meta,
    const int* __restrict__ pairs, unsigned short* __restrict__ hbuf)
{
  int mtile = blockIdx.y;
  if (mtile * 128 >= meta[E_NUM]) return;
  int e = 0;
  while (meta[e + 1] <= mtile * 128) ++e;
  int ntile = blockIdx.x;   // 64 cols of I

  __shared__ alignas(16) unsigned short As[2][128 * 32];
  __shared__ alignas(16) unsigned short B1s[2][64 * 32];
  __shared__ alignas(16) unsigned short B3s[2][64 * 32];
  __shared__ int rowtok[128];

  int tid = threadIdx.x;
  for (int i = tid; i < 128; i += 256) {
    int p = pairs[mtile * 128 + i];
    rowtok[i] = (p >= 0) ? (p >> 1) : -1;
  }
  __syncthreads();

  int lane = tid & 63, w = tid >> 6;
  int wm = w >> 1, wn = w & 1, lrow = lane & 15, quad = lane >> 4;

  // A staging: wave w, issue j: rows 32w+16j + lane/4, 16B chunk lane%4
  size_t axoff[2];
#pragma unroll
  for (int j = 0; j < 2; ++j) {
    int r = 32 * w + 16 * j + (lane >> 2);
    int tok = rowtok[r]; if (tok < 0) tok = 0;
    axoff[j] = (size_t)tok * D_DIM + (lane & 3) * 8;
  }
  // B staging: thread t -> row t/4 (0..63), col (t%4)*8
  const float* pw1 = w1 + ((size_t)e * I_DIM + ntile * 64 + (tid >> 2)) * D_DIM + (tid & 3) * 8;
  const float* pw3 = w3 + ((size_t)e * I_DIM + ntile * 64 + (tid >> 2)) * D_DIM + (tid & 3) * 8;
  int bws = (tid >> 2) * 32 + (tid & 3) * 8;

  f32x4 acc1[4][2], acc3[4][2];
#pragma unroll
  for (int i = 0; i < 4; ++i)
#pragma unroll
    for (int j = 0; j < 2; ++j) {
      acc1[i][j] = (f32x4){0.f, 0.f, 0.f, 0.f};
      acc3[i][j] = (f32x4){0.f, 0.f, 0.f, 0.f};
    }

  // prologue: K-tile 0
  float4 r1[2], r3[2];
  r1[0] = *(const float4*)(pw1);     r1[1] = *(const float4*)(pw1 + 4);
  r3[0] = *(const float4*)(pw3);     r3[1] = *(const float4*)(pw3 + 4);
  gload_lds16(xbf + axoff[0], &As[0][(32 * w) * 32]);
  gload_lds16(xbf + axoff[1], &As[0][(32 * w + 16) * 32]);
  *(uint4*)&B1s[0][bws] = pack8(r1[0], r1[1]);
  *(uint4*)&B3s[0][bws] = pack8(r3[0], r3[1]);

  const int KT = D_DIM / 32;   // 32
  for (int k = 0; k < KT; ++k) {
    __syncthreads();
    int kk = k & 1;
    if (k + 1 < KT) {
      int kn = (k + 1) * 32;
      r1[0] = *(const float4*)(pw1 + kn); r1[1] = *(const float4*)(pw1 + kn + 4);
      r3[0] = *(const float4*)(pw3 + kn); r3[1] = *(const float4*)(pw3 + kn + 4);
      gload_lds16(xbf + axoff[0] + kn, &As[kk ^ 1][(32 * w) * 32]);
      gload_lds16(xbf + axoff[1] + kn, &As[kk ^ 1][(32 * w + 16) * 32]);
    }
    bf16x8 af[4];
#pragma unroll
    for (int mi = 0; mi < 4; ++mi)
      af[mi] = *(const bf16x8*)&As[kk][(wm * 64 + mi * 16 + lrow) * 32 + quad * 8];
#pragma unroll
    for (int ni = 0; ni < 2; ++ni) {
      bf16x8 b1 = *(const bf16x8*)&B1s[kk][(wn * 32 + ni * 16 + lrow) * 32 + quad * 8];
#pragma unroll
      for (int mi = 0; mi < 4; ++mi)
        acc1[mi][ni] = __builtin_amdgcn_mfma_f32_16x16x32_bf16(af[mi], b1, acc1[mi][ni], 0, 0, 0);
      bf16x8 b3 = *(const bf16x8*)&B3s[kk][(wn * 32 + ni * 16 + lrow) * 32 + quad * 8];
#pragma unroll
      for (int mi = 0; mi < 4; ++mi)
        acc3[mi][ni] = __builtin_amdgcn_mfma_f32_16x16x32_bf16(af[mi], b3, acc3[mi][ni], 0, 0, 0);
    }
    if (k + 1 < KT) {
      *(uint4*)&B1s[kk ^ 1][bws] = pack8(r1[0], r1[1]);
      *(uint4*)&B3s[kk ^ 1][bws] = pack8(r3[0], r3[1]);
    }
  }

  // epilogue: h = silu(a1)*a3 -> bf16 (padded row index)
#pragma unroll
  for (int mi = 0; mi < 4; ++mi) {
#pragma unroll
    for (int r = 0; r < 4; ++r) {
      int lr = wm * 64 + mi * 16 + quad * 4 + r;
      if (rowtok[lr] >= 0) {
        size_t base = (size_t)(mtile * 128 + lr) * I_DIM + (size_t)ntile * 64 + wn * 32;
#pragma unroll
        for (int ni = 0; ni < 2; ++ni) {
          float v1 = acc1[mi][ni][r];
          float v3 = acc3[mi][ni][r];
          float hv = (v1 / (1.f + __expf(-v1))) * v3;
          hbuf[base + ni * 16 + lrow] = f2bf(hv);
        }
      }
    }
  }
}

// ---------------- stage2: out += h w2^T (split-K, atomic) ---------------------
// grid (8, 24, 4), block 256 = 4 waves (2x2), wave-tile 64x64. BK=32 dbuf.
__global__ __launch_bounds__(256, 3) void stage2_v4(
    const unsigned short* __restrict__ hbuf, const float* __restrict__ w2,
    const int* __restrict__ meta, const int* __restrict__ pairs,
    float* __restrict__ out)
{
  int mtile = blockIdx.y;
  if (mtile * 128 >= meta[E_NUM]) return;
  int e = 0;
  while (meta[e + 1] <= mtile * 128) ++e;
  int ntile = blockIdx.x;           // 128 cols of D
  int kbase = blockIdx.z * KCHUNK;  // 704-wide K chunk

  __shared__ alignas(16) unsigned short As[2][128 * 32];
  __shared__ alignas(16) unsigned short Bs[2][128 * 32];
  __shared__ int prow[128];

  int tid = threadIdx.x;
  for (int i = tid; i < 128; i += 256) prow[i] = pairs[mtile * 128 + i];
  __syncthreads();

  int lane = tid & 63, w = tid >> 6;
  int wm = w >> 1, wn = w & 1, lrow = lane & 15, quad = lane >> 4;

  // A staging (hbuf, bf16): wave w, issue j: rows 32w+16j+(lane/4)
  size_t axoff[2];
#pragma unroll
  for (int j = 0; j < 2; ++j) {
    int r = 32 * w + 16 * j + (lane >> 2);
    axoff[j] = (size_t)(mtile * 128 + r) * I_DIM + kbase + (lane & 3) * 8;
  }
  // B staging (w2, fp32): thread t, issue j: row j*64 + t/4, col (t%4)*8
  const float* pw2[2];
  int bws[2];
#pragma unroll
  for (int j = 0; j < 2; ++j) {
    int row = j * 64 + (tid >> 2);
    pw2[j] = w2 + ((size_t)e * D_DIM + ntile * 128 + row) * I_DIM + kbase + (tid & 3) * 8;
    bws[j] = row * 32 + (tid & 3) * 8;
  }

  f32x4 acc[4][4];
#pragma unroll
  for (int i = 0; i < 4; ++i)
#pragma unroll
    for (int j = 0; j < 4; ++j) acc[i][j] = (f32x4){0.f, 0.f, 0.f, 0.f};

  // prologue
  float4 rb[2][2];
#pragma unroll
  for (int j = 0; j < 2; ++j) {
    rb[j][0] = *(const float4*)(pw2[j]);
    rb[j][1] = *(const float4*)(pw2[j] + 4);
    gload_lds16(hbuf + axoff[j], &As[0][(32 * w + 16 * j) * 32]);
  }
#pragma unroll
  for (int j = 0; j < 2; ++j)
    *(uint4*)&Bs[0][bws[j]] = pack8(rb[j][0], rb[j][1]);

  for (int k = 0; k < KT2; ++k) {
    __syncthreads();
    int kk = k & 1;
    if (k + 1 < KT2) {
      int kn = (k + 1) * 32;
#pragma unroll
      for (int j = 0; j < 2; ++j) {
        rb[j][0] = *(const float4*)(pw2[j] + kn);
        rb[j][1] = *(const float4*)(pw2[j] + kn + 4);
        gload_lds16(hbuf + axoff[j] + kn, &As[kk ^ 1][(32 * w + 16 * j) * 32]);
      }
    }
    bf16x8 af[4];
#pragma unroll
    for (int mi = 0; mi < 4; ++mi)
      af[mi] = *(const bf16x8*)&As[kk][(wm * 64 + mi * 16 + lrow) * 32 + quad * 8];
#pragma unroll
    for (int ni = 0; ni < 4; ++ni) {
      bf16x8 bfr = *(const bf16x8*)&Bs[kk][(wn * 64 + ni * 16 + lrow) * 32 + quad * 8];
#pragma unroll
      for (int mi = 0; mi < 4; ++mi)
        acc[mi][ni] = __builtin_amdgcn_mfma_f32_16x16x32_bf16(af[mi], bfr, acc[mi][ni], 0, 0, 0);
    }
    if (k + 1 < KT2) {
#pragma unroll
      for (int j = 0; j < 2; ++j)
        *(uint4*)&Bs[kk ^ 1][bws[j]] = pack8(rb[j][0], rb[j][1]);
    }
  }

  // epilogue: atomic accumulate partials
#pragma unroll
  for (int mi = 0; mi < 4; ++mi) {
#pragma unroll
    for (int r = 0; r < 4; ++r) {
      int lr = wm * 64 + mi * 16 + quad * 4 + r;
      int p = prow[lr];
      if (p >= 0) {
        float* obase = out + (size_t)p * D_DIM + (size_t)ntile * 128 + wn * 64;
#pragma unroll
        for (int ni = 0; ni < 4; ++ni)
          atomicAdd(obase + ni * 16 + lrow, acc[mi][ni][r]);
      }
    }
  }
}

extern "C" void kernel_launch(void* const* d_in, const int* in_sizes, int n_in,
                              void* d_out, int out_size, void* d_ws, size_t ws_size,
                              hipStream_t stream) {
  const float* x  = (const float*)d_in[0];
  const float* w1 = (const float*)d_in[1];
  const float* w2 = (const float*)d_in[2];
  const float* w3 = (const float*)d_in[3];
  const int* eidx = (const int*)d_in[4];
  float* out = (float*)d_out;

  int* meta  = (int*)d_ws;
  int* pairs = (int*)((char*)d_ws + 64);
  unsigned short* hbuf = (unsigned short*)((char*)d_ws + HB_OFF);
  unsigned short* xbf  = (unsigned short*)((char*)d_ws + XBF_OFF);

  sort_pairs_kernel<<<1, 256, 0, stream>>>(eidx, meta, pairs);
  convertx_kernel<<<(T_NUM * D_DIM) / 8 / 256, 256, 0, stream>>>(x, xbf);
  hipMemsetAsync(out, 0, (size_t)out_size * sizeof(float), stream);

  dim3 g1(I_DIM / 64, MT_MAX);            // 44 x 24
  stage1_v4<<<g1, 256, 0, stream>>>(xbf, w1, w3, meta, pairs, hbuf);
  dim3 g2(D_DIM / 128, MT_MAX, KSPLIT);   // 8 x 24 x 4
  stage2_v4<<<g2, 256, 0, stream>>>(hbuf, w2, meta, pairs, out);
}

// Round 5
// 337.553 us; speedup vs baseline: 2.0433x; 1.0316x over previous
//
#include <hip/hip_runtime.h>
#include <hip/hip_bf16.h>

#define E_NUM 8
#define I_DIM 2816
#define D_DIM 1024
#define T_NUM 1024
#define A_TOP 2
#define NPAIR (T_NUM * A_TOP)   // 2048
#define PADROWS 3072            // worst-case 128-padded rows
#define MT_MAX (PADROWS / 128)  // 24
#define KSPLIT 4
#define KCHUNK (I_DIM / KSPLIT) // 704
#define KT2 (KCHUNK / 32)       // 22

// ws layout: [0,64) meta, [64,+PADROWS*4) pairs, hbuf @16384, xbf after
#define HB_OFF    16384ULL
#define HB_BYTES  ((unsigned long long)PADROWS * I_DIM * 2ULL)
#define XBF_OFF   (HB_OFF + HB_BYTES)

typedef __bf16 bf16x8 __attribute__((ext_vector_type(8)));
typedef float  f32x4  __attribute__((ext_vector_type(4)));

// packed fp32->bf16 RNE via native v_cvt_pk_bf16_f32 (through hip_bf16.h)
__device__ inline unsigned pk2(float a, float b) {
  __hip_bfloat162 h = __float22bfloat162_rn(make_float2(a, b));
  union { __hip_bfloat162 h; unsigned u; } c; c.h = h; return c.u;
}
__device__ inline uint4 pack8(float4 a, float4 b) {
  return make_uint4(pk2(a.x, a.y), pk2(a.z, a.w), pk2(b.x, b.y), pk2(b.z, b.w));
}
__device__ inline unsigned short f2bf(float f) {
  __hip_bfloat16 h = __float2bfloat16(f);
  union { __hip_bfloat16 h; unsigned short u; } c; c.h = h; return c.u;
}
__device__ inline void gload_lds16(const unsigned short* g, unsigned short* l) {
  __builtin_amdgcn_global_load_lds((const __attribute__((address_space(1))) void*)g,
                                   (__attribute__((address_space(3))) void*)l, 16, 0, 0);
}

// ---------------- kernel 1: bucket pairs by expert, 128-padded segments -------
__global__ __launch_bounds__(256) void sort_pairs_kernel(
    const int* __restrict__ eidx, int* __restrict__ meta, int* __restrict__ pairs)
{
  __shared__ int cnt[E_NUM];
  __shared__ int pstart[E_NUM + 1];
  __shared__ int cur[E_NUM];
  int tid = threadIdx.x;
  if (tid < E_NUM) cnt[tid] = 0;
  __syncthreads();
  for (int p = tid; p < NPAIR; p += 256) atomicAdd(&cnt[eidx[p] & 7], 1);
  for (int i = tid; i < PADROWS; i += 256) pairs[i] = -1;
  __syncthreads();
  if (tid == 0) {
    int s = 0;
    for (int e = 0; e < E_NUM; ++e) {
      pstart[e] = s; cur[e] = s;
      s += ((cnt[e] + 127) / 128) * 128;
    }
    pstart[E_NUM] = s;
  }
  __syncthreads();
  for (int p = tid; p < NPAIR; p += 256) {
    int e = eidx[p] & 7;
    int pos = atomicAdd(&cur[e], 1);
    pairs[pos] = p;
  }
  __syncthreads();
  if (tid <= E_NUM) meta[tid] = pstart[tid];
}

// ---------------- x: fp32 -> bf16 ----------------
__global__ __launch_bounds__(256) void convertx_kernel(
    const float* __restrict__ in, unsigned short* __restrict__ out)
{
  size_t i = (size_t)(blockIdx.x * 256 + threadIdx.x) * 8;
  const float4* p = (const float4*)(in + i);
  *(uint4*)(out + i) = pack8(p[0], p[1]);
}

// ---------------- stage1: h = silu(X w1^T) * (X w3^T) -------------------------
// grid (44, 24), block 256 = 4 waves (2x2), wave-tile 64x32. BK=32 dbuf.
__global__ __launch_bounds__(256, 4) void stage1_v5(
    const unsigned short* __restrict__ xbf, const float* __restrict__ w1,
    const float* __restrict__ w3, const int* __restrict__ meta,
    const int* __restrict__ pairs, unsigned short* __restrict__ hbuf)
{
  int mtile = blockIdx.y;
  if (mtile * 128 >= meta[E_NUM]) return;
  int e = 0;
  while (meta[e + 1] <= mtile * 128) ++e;
  int ntile = blockIdx.x;   // 64 cols of I

  __shared__ alignas(16) unsigned short As[2][128 * 32];
  __shared__ alignas(16) unsigned short B1s[2][64 * 32];
  __shared__ alignas(16) unsigned short B3s[2][64 * 32];
  __shared__ int rowtok[128];

  int tid = threadIdx.x;
  for (int i = tid; i < 128; i += 256) {
    int p = pairs[mtile * 128 + i];
    rowtok[i] = (p >= 0) ? (p >> 1) : -1;
  }
  __syncthreads();

  int lane = tid & 63, w = tid >> 6;
  int wm = w >> 1, wn = w & 1, lrow = lane & 15, quad = lane >> 4;

  // A staging: wave w, issue j: rows 32w+16j + lane/4, 16B chunk lane%4
  size_t axoff[2];
#pragma unroll
  for (int j = 0; j < 2; ++j) {
    int r = 32 * w + 16 * j + (lane >> 2);
    int tok = rowtok[r]; if (tok < 0) tok = 0;
    axoff[j] = (size_t)tok * D_DIM + (lane & 3) * 8;
  }
  // B staging: thread t -> row t/4 (0..63), col (t%4)*8
  const float* pw1 = w1 + ((size_t)e * I_DIM + ntile * 64 + (tid >> 2)) * D_DIM + (tid & 3) * 8;
  const float* pw3 = w3 + ((size_t)e * I_DIM + ntile * 64 + (tid >> 2)) * D_DIM + (tid & 3) * 8;
  int bws = (tid >> 2) * 32 + (tid & 3) * 8;

  f32x4 acc1[4][2], acc3[4][2];
#pragma unroll
  for (int i = 0; i < 4; ++i)
#pragma unroll
    for (int j = 0; j < 2; ++j) {
      acc1[i][j] = (f32x4){0.f, 0.f, 0.f, 0.f};
      acc3[i][j] = (f32x4){0.f, 0.f, 0.f, 0.f};
    }

  // prologue: K-tile 0
  float4 r1[2], r3[2];
  r1[0] = *(const float4*)(pw1);     r1[1] = *(const float4*)(pw1 + 4);
  r3[0] = *(const float4*)(pw3);     r3[1] = *(const float4*)(pw3 + 4);
  gload_lds16(xbf + axoff[0], &As[0][(32 * w) * 32]);
  gload_lds16(xbf + axoff[1], &As[0][(32 * w + 16) * 32]);
  *(uint4*)&B1s[0][bws] = pack8(r1[0], r1[1]);
  *(uint4*)&B3s[0][bws] = pack8(r3[0], r3[1]);

  const int KT = D_DIM / 32;   // 32
  for (int k = 0; k < KT; ++k) {
    __syncthreads();
    int kk = k & 1;
    if (k + 1 < KT) {
      int kn = (k + 1) * 32;
      r1[0] = *(const float4*)(pw1 + kn); r1[1] = *(const float4*)(pw1 + kn + 4);
      r3[0] = *(const float4*)(pw3 + kn); r3[1] = *(const float4*)(pw3 + kn + 4);
      gload_lds16(xbf + axoff[0] + kn, &As[kk ^ 1][(32 * w) * 32]);
      gload_lds16(xbf + axoff[1] + kn, &As[kk ^ 1][(32 * w + 16) * 32]);
    }
    bf16x8 af[4];
#pragma unroll
    for (int mi = 0; mi < 4; ++mi)
      af[mi] = *(const bf16x8*)&As[kk][(wm * 64 + mi * 16 + lrow) * 32 + quad * 8];
#pragma unroll
    for (int ni = 0; ni < 2; ++ni) {
      bf16x8 b1 = *(const bf16x8*)&B1s[kk][(wn * 32 + ni * 16 + lrow) * 32 + quad * 8];
#pragma unroll
      for (int mi = 0; mi < 4; ++mi)
        acc1[mi][ni] = __builtin_amdgcn_mfma_f32_16x16x32_bf16(af[mi], b1, acc1[mi][ni], 0, 0, 0);
      bf16x8 b3 = *(const bf16x8*)&B3s[kk][(wn * 32 + ni * 16 + lrow) * 32 + quad * 8];
#pragma unroll
      for (int mi = 0; mi < 4; ++mi)
        acc3[mi][ni] = __builtin_amdgcn_mfma_f32_16x16x32_bf16(af[mi], b3, acc3[mi][ni], 0, 0, 0);
    }
    if (k + 1 < KT) {
      *(uint4*)&B1s[kk ^ 1][bws] = pack8(r1[0], r1[1]);
      *(uint4*)&B3s[kk ^ 1][bws] = pack8(r3[0], r3[1]);
    }
  }

  // epilogue: h = silu(a1)*a3 -> bf16 (padded row index)
#pragma unroll
  for (int mi = 0; mi < 4; ++mi) {
#pragma unroll
    for (int r = 0; r < 4; ++r) {
      int lr = wm * 64 + mi * 16 + quad * 4 + r;
      if (rowtok[lr] >= 0) {
        size_t base = (size_t)(mtile * 128 + lr) * I_DIM + (size_t)ntile * 64 + wn * 32;
#pragma unroll
        for (int ni = 0; ni < 2; ++ni) {
          float v1 = acc1[mi][ni][r];
          float v3 = acc3[mi][ni][r];
          float hv = (v1 / (1.f + __expf(-v1))) * v3;
          hbuf[base + ni * 16 + lrow] = f2bf(hv);
        }
      }
    }
  }
}

// ---------------- stage2: out += h w2^T (split-K, atomic) ---------------------
// grid (8, 24, 4), block 256 = 4 waves (2x2), wave-tile 64x64. BK=32 dbuf.
__global__ __launch_bounds__(256, 4) void stage2_v5(
    const unsigned short* __restrict__ hbuf, const float* __restrict__ w2,
    const int* __restrict__ meta, const int* __restrict__ pairs,
    float* __restrict__ out)
{
  int mtile = blockIdx.y;
  if (mtile * 128 >= meta[E_NUM]) return;
  int e = 0;
  while (meta[e + 1] <= mtile * 128) ++e;
  int ntile = blockIdx.x;           // 128 cols of D
  int kbase = blockIdx.z * KCHUNK;  // 704-wide K chunk

  __shared__ alignas(16) unsigned short As[2][128 * 32];
  __shared__ alignas(16) unsigned short Bs[2][128 * 32];
  __shared__ int prow[128];

  int tid = threadIdx.x;
  for (int i = tid; i < 128; i += 256) prow[i] = pairs[mtile * 128 + i];
  __syncthreads();

  int lane = tid & 63, w = tid >> 6;
  int wm = w >> 1, wn = w & 1, lrow = lane & 15, quad = lane >> 4;

  // A staging (hbuf, bf16): wave w, issue j: rows 32w+16j+(lane/4)
  size_t axoff[2];
#pragma unroll
  for (int j = 0; j < 2; ++j) {
    int r = 32 * w + 16 * j + (lane >> 2);
    axoff[j] = (size_t)(mtile * 128 + r) * I_DIM + kbase + (lane & 3) * 8;
  }
  // B staging (w2, fp32): thread t, issue j: row j*64 + t/4, col (t%4)*8
  const float* pw2[2];
  int bws[2];
#pragma unroll
  for (int j = 0; j < 2; ++j) {
    int row = j * 64 + (tid >> 2);
    pw2[j] = w2 + ((size_t)e * D_DIM + ntile * 128 + row) * I_DIM + kbase + (tid & 3) * 8;
    bws[j] = row * 32 + (tid & 3) * 8;
  }

  f32x4 acc[4][4];
#pragma unroll
  for (int i = 0; i < 4; ++i)
#pragma unroll
    for (int j = 0; j < 4; ++j) acc[i][j] = (f32x4){0.f, 0.f, 0.f, 0.f};

  // prologue
  float4 rb[2][2];
#pragma unroll
  for (int j = 0; j < 2; ++j) {
    rb[j][0] = *(const float4*)(pw2[j]);
    rb[j][1] = *(const float4*)(pw2[j] + 4);
    gload_lds16(hbuf + axoff[j], &As[0][(32 * w + 16 * j) * 32]);
  }
#pragma unroll
  for (int j = 0; j < 2; ++j)
    *(uint4*)&Bs[0][bws[j]] = pack8(rb[j][0], rb[j][1]);

  for (int k = 0; k < KT2; ++k) {
    __syncthreads();
    int kk = k & 1;
    if (k + 1 < KT2) {
      int kn = (k + 1) * 32;
#pragma unroll
      for (int j = 0; j < 2; ++j) {
        rb[j][0] = *(const float4*)(pw2[j] + kn);
        rb[j][1] = *(const float4*)(pw2[j] + kn + 4);
        gload_lds16(hbuf + axoff[j] + kn, &As[kk ^ 1][(32 * w + 16 * j) * 32]);
      }
    }
    bf16x8 af[4];
#pragma unroll
    for (int mi = 0; mi < 4; ++mi)
      af[mi] = *(const bf16x8*)&As[kk][(wm * 64 + mi * 16 + lrow) * 32 + quad * 8];
#pragma unroll
    for (int ni = 0; ni < 4; ++ni) {
      bf16x8 bfr = *(const bf16x8*)&Bs[kk][(wn * 64 + ni * 16 + lrow) * 32 + quad * 8];
#pragma unroll
      for (int mi = 0; mi < 4; ++mi)
        acc[mi][ni] = __builtin_amdgcn_mfma_f32_16x16x32_bf16(af[mi], bfr, acc[mi][ni], 0, 0, 0);
    }
    if (k + 1 < KT2) {
#pragma unroll
      for (int j = 0; j < 2; ++j)
        *(uint4*)&Bs[kk ^ 1][bws[j]] = pack8(rb[j][0], rb[j][1]);
    }
  }

  // epilogue: atomic accumulate partials
#pragma unroll
  for (int mi = 0; mi < 4; ++mi) {
#pragma unroll
    for (int r = 0; r < 4; ++r) {
      int lr = wm * 64 + mi * 16 + quad * 4 + r;
      int p = prow[lr];
      if (p >= 0) {
        float* obase = out + (size_t)p * D_DIM + (size_t)ntile * 128 + wn * 64;
#pragma unroll
        for (int ni = 0; ni < 4; ++ni)
          atomicAdd(obase + ni * 16 + lrow, acc[mi][ni][r]);
      }
    }
  }
}

extern "C" void kernel_launch(void* const* d_in, const int* in_sizes, int n_in,
                              void* d_out, int out_size, void* d_ws, size_t ws_size,
                              hipStream_t stream) {
  const float* x  = (const float*)d_in[0];
  const float* w1 = (const float*)d_in[1];
  const float* w2 = (const float*)d_in[2];
  const float* w3 = (const float*)d_in[3];
  const int* eidx = (const int*)d_in[4];
  float* out = (float*)d_out;

  int* meta  = (int*)d_ws;
  int* pairs = (int*)((char*)d_ws + 64);
  unsigned short* hbuf = (unsigned short*)((char*)d_ws + HB_OFF);
  unsigned short* xbf  = (unsigned short*)((char*)d_ws + XBF_OFF);

  sort_pairs_kernel<<<1, 256, 0, stream>>>(eidx, meta, pairs);
  convertx_kernel<<<(T_NUM * D_DIM) / 8 / 256, 256, 0, stream>>>(x, xbf);
  hipMemsetAsync(out, 0, (size_t)out_size * sizeof(float), stream);

  dim3 g1(I_DIM / 64, MT_MAX);            // 44 x 24
  stage1_v5<<<g1, 256, 0, stream>>>(xbf, w1, w3, meta, pairs, hbuf);
  dim3 g2(D_DIM / 128, MT_MAX, KSPLIT);   // 8 x 24 x 4
  stage2_v5<<<g2, 256, 0, stream>>>(hbuf, w2, meta, pairs, out);
}